// Round 10
// baseline (313.608 us; speedup 1.0000x reference)
//
#include <hip/hip_runtime.h>
#include <cstddef>

typedef __attribute__((ext_vector_type(8))) short short8;
typedef __attribute__((ext_vector_type(4))) short short4v;
typedef __attribute__((ext_vector_type(4))) float floatx4;

// ---------------------------------------------------------------- bf16 utils
__device__ __forceinline__ unsigned short f2bf(float f) {
  union { float f; unsigned u; } v; v.f = f;
  const unsigned r = v.u + 0x7fffu + ((v.u >> 16) & 1u);  // RNE
  return (unsigned short)(r >> 16);
}

// ---------------------------------------------------------------- reductions
__device__ __forceinline__ float block_reduce_sum(float v, float* sm) {
#pragma unroll
  for (int off = 32; off > 0; off >>= 1) v += __shfl_down(v, off, 64);
  const int lane = threadIdx.x & 63, wid = threadIdx.x >> 6;
  __syncthreads();
  if (lane == 0) sm[wid] = v;
  __syncthreads();
  if (threadIdx.x == 0) {
    float t = 0.f;
    const int nw = (blockDim.x + 63) >> 6;
    for (int i = 0; i < nw; ++i) t += sm[i];
    sm[0] = t;
  }
  __syncthreads();
  return sm[0];
}

// ---------------------------------------------------------------- ternarize
// red[t*4+0]=sum|w|, red[t*4+1]=masked count, red[t*4+2]=masked sum|w|.
__device__ __forceinline__ void tsel(int t, const float* w0, const float* w1,
                                     const float* w2, const float* w3, int n0,
                                     int n1, int n2, int n3,
                                     const float*& w, int& n) {
  w = (t == 0) ? w0 : (t == 1) ? w1 : (t == 2) ? w2 : w3;
  n = (t == 0) ? n0 : (t == 1) ? n1 : (t == 2) ? n2 : n3;
}

__global__ __launch_bounds__(256) void tern_phase1(
    const float* w0, const float* w1, const float* w2, const float* w3,
    int n0, int n1, int n2, int n3, float* __restrict__ red) {
  __shared__ float sm[8];
  const float* w; int n;
  tsel(blockIdx.y, w0, w1, w2, w3, n0, n1, n2, n3, w, n);
  if ((int)blockIdx.x * 256 >= n) return;
  const int i = blockIdx.x * 256 + threadIdx.x;
  float s = (i < n) ? fabsf(w[i]) : 0.f;
  s = block_reduce_sum(s, sm);
  if (threadIdx.x == 0) atomicAdd(&red[blockIdx.y * 4 + 0], s);
}

__global__ __launch_bounds__(256) void tern_phase2(
    const float* w0, const float* w1, const float* w2, const float* w3,
    int n0, int n1, int n2, int n3, float* __restrict__ red) {
  __shared__ float sm[8];
  const float* w; int n;
  tsel(blockIdx.y, w0, w1, w2, w3, n0, n1, n2, n3, w, n);
  if ((int)blockIdx.x * 256 >= n) return;
  const float delta = 0.7f * red[blockIdx.y * 4 + 0] / (float)n;
  const int i = blockIdx.x * 256 + threadIdx.x;
  float c = 0.f, a = 0.f;
  if (i < n) {
    const float v = fabsf(w[i]);
    if (v > delta) { c = 1.f; a = v; }
  }
  c = block_reduce_sum(c, sm);
  a = block_reduce_sum(a, sm);
  if (threadIdx.x == 0) {
    atomicAdd(&red[blockIdx.y * 4 + 1], c);
    atomicAdd(&red[blockIdx.y * 4 + 2], a);
  }
}

// ---------------------------------------------------------------- prep (merged)
// block 0: BN folds; 1-4: conv1 signs; 5-9: wl ternarize; 10-81: w2t pack;
// 82-369: w3t pack.
// w2t (transposed-A layout): idx = ((tap*4+quad)*64 + och2)*8 + j,
//   value = sign(w2[och2][ch1=quad*8+j][kh][kw])  (bf16 +/-1/0)
// w3t: idx = (((tap*2+h)*4+quad)*128 + och3)*8 + j, ch2 = h*32+quad*8+j
__global__ __launch_bounds__(256) void prep_all(
    const float* w1, const float* w2, const float* w3, const float* wl,
    const float* g1, const float* b1, const float* m1, const float* v1,
    const float* g2, const float* b2, const float* m2, const float* v2,
    const float* g3, const float* b3, const float* m3, const float* v3,
    const float* __restrict__ red, float* q1t, float* ql,
    float* s1, float* bb1, float* s2, float* bb2, float* s3, float* bb3,
    unsigned short* w2t, unsigned short* w3t) {
  const int b = blockIdx.x, t = threadIdx.x;
  if (b == 0) {
    if (t < 32) {
      const float inv = g1[t] / sqrtf(v1[t] + 1e-5f);
      const float a = red[2] / fmaxf(red[1], 1.f);
      s1[t] = a * inv; bb1[t] = b1[t] - m1[t] * inv;
    } else if (t < 96) {
      const int c = t - 32;
      const float inv = g2[c] / sqrtf(v2[c] + 1e-5f);
      const float a = red[6] / fmaxf(red[5], 1.f);
      s2[c] = a * inv; bb2[c] = b2[c] - m2[c] * inv;
    } else if (t < 224) {
      const int c = t - 96;
      const float inv = g3[c] / sqrtf(v3[c] + 1e-5f);
      const float a = red[10] / fmaxf(red[9], 1.f);
      s3[c] = a * inv; bb3[c] = b3[c] - m3[c] * inv;
    }
  } else if (b <= 4) {
    const int idx = (b - 1) * 256 + t;  // conv1 signs, tap-major
    if (idx < 864) {
      const float delta = 0.7f * red[0] / 864.f;
      const int tap = idx / 32, oc = idx % 32;
      const int ic = tap / 9, kh = (tap % 9) / 3, kw = tap % 3;
      const float v = w1[((oc * 3 + ic) * 3 + kh) * 3 + kw];
      q1t[idx] = (v > delta) ? 1.f : (v < -delta ? -1.f : 0.f);
    }
  } else if (b <= 9) {
    const int i = (b - 5) * 256 + t;  // wl: fp32 +/-alpha / 0
    if (i < 1280) {
      const float delta = 0.7f * red[12] / 1280.f;
      const float alpha = red[14] / fmaxf(red[13], 1.f);
      const float wi = wl[i];
      ql[i] = (fabsf(wi) > delta) ? copysignf(alpha, wi) : 0.f;
    }
  } else if (b <= 81) {
    const int idx = (b - 10) * 256 + t;  // w2t
    const float delta = 0.7f * red[4] / 18432.f;
    const int j = idx & 7, och2 = (idx >> 3) & 63;
    const int quad = (idx >> 9) & 3, tap = idx >> 11;
    const int ch1 = quad * 8 + j;
    const int kh = tap / 3, kw = tap % 3;
    const float v = w2[(((size_t)och2 * 32 + ch1) * 3 + kh) * 3 + kw];
    w2t[idx] = (v > delta) ? 0x3F80u : (v < -delta ? 0xBF80u : 0u);
  } else {
    const int idx = (b - 82) * 256 + t;  // w3t
    const float delta = 0.7f * red[8] / 73728.f;
    const int j = idx & 7, och3 = (idx >> 3) & 127;
    const int quad = (idx >> 10) & 3, h = (idx >> 12) & 1, tap = idx >> 13;
    const int ch2 = h * 32 + quad * 8 + j;
    const int kh = tap / 3, kw = tap % 3;
    const float v = w3[(((size_t)och3 * 64 + ch2) * 3 + kh) * 3 + kw];
    w3t[idx] = (v > delta) ? 0x3F80u : (v < -delta ? 0xBF80u : 0u);
  }
}

// ---------------------------------------------------------------- conv1 v2
__global__ __launch_bounds__(256) void conv1_v2(
    const float* __restrict__ x, const float* __restrict__ q1t,
    const float* __restrict__ scale, const float* __restrict__ bias,
    unsigned short* __restrict__ y) {
  __shared__ float xs[15 * 225];  // [ic*5 + dr][slot], slot = iw+1
  const int n = blockIdx.y;
  const int oh0 = blockIdx.x * 2;
  const int t = threadIdx.x;
  const int ih_base = oh0 * 2 - 1;
  for (int idx = t; idx < 15 * 225; idx += 256) {
    const int row = idx / 225, s = idx % 225;
    const int ic = row / 5, dr = row % 5;
    const int ih = ih_base + dr, iw = s - 1;
    float v = 0.f;
    if ((unsigned)ih < 224u && (unsigned)iw < 224u)
      v = x[((size_t)n * 3 + ic) * 50176 + (size_t)ih * 224 + iw];
    xs[idx] = v;
  }
  __syncthreads();
  if (t >= 224) return;
  const int r = t / 112, ow = t % 112;
  float acc[32];
#pragma unroll
  for (int j = 0; j < 32; ++j) acc[j] = 0.f;
#pragma unroll
  for (int ic = 0; ic < 3; ++ic)
#pragma unroll
    for (int kh = 0; kh < 3; ++kh) {
      const float* xr = &xs[(ic * 5 + r * 2 + kh) * 225 + 2 * ow];
      const float xv0 = xr[0], xv1 = xr[1], xv2 = xr[2];
#pragma unroll
      for (int kw = 0; kw < 3; ++kw) {
        const float xv = (kw == 0) ? xv0 : (kw == 1) ? xv1 : xv2;
        const float* wrow = &q1t[(ic * 9 + kh * 3 + kw) * 32];
#pragma unroll
        for (int j = 0; j < 32; ++j) acc[j] += xv * wrow[j];
      }
    }
  const int oh = oh0 + r;
  unsigned pk[16];
#pragma unroll
  for (int h = 0; h < 16; ++h) {
    const float a0 = fmaxf(acc[2 * h] * scale[2 * h] + bias[2 * h], 0.f);
    const float a1 = fmaxf(acc[2 * h + 1] * scale[2 * h + 1] + bias[2 * h + 1], 0.f);
    pk[h] = (unsigned)f2bf(a0) | ((unsigned)f2bf(a1) << 16);
  }
  unsigned short* dst = y + (((size_t)n * 112 + oh) * 112 + ow) * 32;
#pragma unroll
  for (int v = 0; v < 4; ++v)
    *(uint4*)(dst + v * 8) = make_uint4(pk[4 * v], pk[4 * v + 1],
                                        pk[4 * v + 2], pk[4 * v + 3]);
}

// ---------------------------------------------------------------- fused conv2+3+pool (transposed)
// Block = one 8x8 conv3 output tile of one image (grid 49 x 64).
// Both GEMMs computed TRANSPOSED: C^T = W^T x Act^T. A-operand = weights
// (layout chosen at pack time, k=ch inner -> 16B global load, L2-hot);
// B-operand = activations with k=ch inner (NHWC LDS: ds_read_b128 for conv2,
// two aligned ds_read_b64 for conv3). Output C-layout then gives each lane 4
// CONSECUTIVE CHANNELS of one pixel -> the conv2->conv3 LDS hand-off is one
// 8B ds_write_b64 per frag (R8's 80 scalar-u16 scatter cost eliminated).
// c2t rows padded to 36 shorts -> write lanes hit 16 distinct banks.
// LDS: act1 patch (23.1KB) aliased with c2t (20.8KB). act2 never in HBM.
// Pool: BN3+ReLU in-register, shfl-xor over 16 px lanes, LDS combine,
// 128 atomics/block.
__global__ __launch_bounds__(256) void conv23_fused(
    const unsigned short* __restrict__ act1,
    const unsigned short* __restrict__ w2t,
    const unsigned short* __restrict__ w3t,
    const float* __restrict__ s2, const float* __restrict__ bb2,
    const float* __restrict__ s3, const float* __restrict__ bb3,
    float* __restrict__ pooled) {
  __shared__ unsigned short lds[11552];  // union: patch 19*19*4*8 / c2t 289*36
  __shared__ float pbuf[128];
  const int t = threadIdx.x;
  const int img = blockIdx.y;
  const int ty = blockIdx.x / 7, tx = blockIdx.x % 7;
  const int o3h0 = ty * 8, o3w0 = tx * 8;
  const int wave = t >> 6, lane = t & 63, quad = lane >> 4, l16 = lane & 15;

  if (t < 128) pbuf[t] = 0.f;

  // ---- stage act1 patch 19x19, seg-major [seg][pi][pj][8ch]
  {
    const int h0 = o3h0 * 2 - 2, w0 = o3w0 * 2 - 2;
    for (int c = t; c < 19 * 19 * 4; c += 256) {
      const int pix = c >> 2, seg = c & 3;
      const int pi = pix / 19, pj = pix % 19;
      const int ih = h0 + pi, iw = w0 + pj;
      uint4 v = make_uint4(0u, 0u, 0u, 0u);
      if ((unsigned)ih < 112u && (unsigned)iw < 112u)
        v = *(const uint4*)(act1 + (((size_t)img * 112 + ih) * 112 + iw) * 32 +
                            seg * 8);
      *(uint4*)(&lds[((seg * 19 + pi) * 19 + pj) * 8]) = v;
    }
  }

  // conv2: wave owns px-frags {wave, wave+4, wave+8, wave+12, wave+16} of 19
  const int nfr = (wave == 3) ? 4 : 5;
  int baddr[5], pxv[5], piw[5], pjw[5];
#pragma unroll
  for (int i = 0; i < 5; ++i) {
    const int frag = wave + 4 * i;
    const int px = frag * 16 + l16;
    pxv[i] = px;
    const int pc = (px < 289) ? px : 288;
    piw[i] = pc / 17;
    pjw[i] = pc % 17;
    baddr[i] = ((quad * 19 + piw[i]) * 19 + pjw[i]) * 8;
  }
  // conv3: wave owns px3-frag = wave (16 of the 64 output px)
  const int p3i = wave * 2 + (l16 >> 3), p3j = l16 & 7;
  const int b3base = ((p3i * 2) * 17 + p3j * 2) * 36 + quad * 8;

  floatx4 acc2[5][4];
#pragma unroll
  for (int i = 0; i < 5; ++i)
#pragma unroll
    for (int f = 0; f < 4; ++f) acc2[i][f] = (floatx4){0.f, 0.f, 0.f, 0.f};
  floatx4 acc3[8];
#pragma unroll
  for (int of = 0; of < 8; ++of) acc3[of] = (floatx4){0.f, 0.f, 0.f, 0.f};

  __syncthreads();  // patch + pbuf ready

  // ---- conv2: 9 taps, K=32 (all ch1), both och-halves accumulated
#pragma unroll
  for (int tap = 0; tap < 9; ++tap) {
    const int kh = tap / 3, kw = tap % 3;
    short8 a[4];
#pragma unroll
    for (int f = 0; f < 4; ++f)
      a[f] = *(const short8*)(w2t +
          ((size_t)(tap * 4 + quad) * 64 + f * 16 + l16) * 8);
    const int toff = (kh * 19 + kw) * 8;
#pragma unroll
    for (int i = 0; i < 5; ++i)
      if (i < nfr) {
        const short8 b = *(const short8*)(&lds[baddr[i] + toff]);
#pragma unroll
        for (int f = 0; f < 4; ++f)
          acc2[i][f] = __builtin_amdgcn_mfma_f32_16x16x32_bf16(
              a[f], b, acc2[i][f], 0, 0, 0);
      }
  }

  // ---- two och2-halves: write c2t, run conv3 taps
#pragma unroll
  for (int h = 0; h < 2; ++h) {
    __syncthreads();  // h0: act1 reads done; h1: conv3-h0 c2t reads done
#pragma unroll
    for (int i = 0; i < 5; ++i)
      if (i < nfr && pxv[i] < 289) {
        const bool zr = (o3h0 == 0 && piw[i] == 0) ||
                        (o3w0 == 0 && pjw[i] == 0);
#pragma unroll
        for (int fl = 0; fl < 2; ++fl) {
          const int f = 2 * h + fl;
          const float4 sc = *(const float4*)&s2[f * 16 + quad * 4];
          const float4 bs = *(const float4*)&bb2[f * 16 + quad * 4];
          const float v0 = zr ? 0.f : fmaxf(acc2[i][f][0] * sc.x + bs.x, 0.f);
          const float v1 = zr ? 0.f : fmaxf(acc2[i][f][1] * sc.y + bs.y, 0.f);
          const float v2 = zr ? 0.f : fmaxf(acc2[i][f][2] * sc.z + bs.z, 0.f);
          const float v3 = zr ? 0.f : fmaxf(acc2[i][f][3] * sc.w + bs.w, 0.f);
          const unsigned u0 = (unsigned)f2bf(v0) | ((unsigned)f2bf(v1) << 16);
          const unsigned u1 = (unsigned)f2bf(v2) | ((unsigned)f2bf(v3) << 16);
          *(uint2*)(&lds[pxv[i] * 36 + fl * 16 + quad * 4]) =
              make_uint2(u0, u1);
        }
      }
    __syncthreads();  // c2t half visible
#pragma unroll
    for (int tap = 0; tap < 9; ++tap) {
      const int kh = tap / 3, kw = tap % 3;
      const int ba = b3base + (kh * 17 + kw) * 36;
      const short4v lo = *(const short4v*)(&lds[ba]);
      const short4v hi = *(const short4v*)(&lds[ba + 4]);
      const short8 b = __builtin_shufflevector(lo, hi, 0, 1, 2, 3, 4, 5, 6, 7);
#pragma unroll
      for (int of = 0; of < 8; ++of) {
        const short8 a = *(const short8*)(w3t +
            ((size_t)((tap * 2 + h) * 4 + quad) * 128 + of * 16 + l16) * 8);
        acc3[of] = __builtin_amdgcn_mfma_f32_16x16x32_bf16(
            a, b, acc3[of], 0, 0, 0);
      }
    }
  }

  // ---- BN3 + ReLU + pool
#pragma unroll
  for (int of = 0; of < 8; ++of) {
    const float4 sc = *(const float4*)&s3[of * 16 + quad * 4];
    const float4 bs = *(const float4*)&bb3[of * 16 + quad * 4];
    float v0 = fmaxf(acc3[of][0] * sc.x + bs.x, 0.f);
    float v1 = fmaxf(acc3[of][1] * sc.y + bs.y, 0.f);
    float v2 = fmaxf(acc3[of][2] * sc.z + bs.z, 0.f);
    float v3 = fmaxf(acc3[of][3] * sc.w + bs.w, 0.f);
#pragma unroll
    for (int m = 1; m < 16; m <<= 1) {
      v0 += __shfl_xor(v0, m);
      v1 += __shfl_xor(v1, m);
      v2 += __shfl_xor(v2, m);
      v3 += __shfl_xor(v3, m);
    }
    if (l16 == 0) {
      atomicAdd(&pbuf[of * 16 + quad * 4 + 0], v0);
      atomicAdd(&pbuf[of * 16 + quad * 4 + 1], v1);
      atomicAdd(&pbuf[of * 16 + quad * 4 + 2], v2);
      atomicAdd(&pbuf[of * 16 + quad * 4 + 3], v3);
    }
  }
  __syncthreads();
  if (t < 128) atomicAdd(&pooled[(size_t)img * 128 + t], pbuf[t]);
}

// ---------------------------------------------------------------- linear
// pooled holds SUMS over 3136 pixels; divide here.
__global__ void linear_kernel(const float* __restrict__ pooled,
                              const float* __restrict__ ql,
                              const float* __restrict__ bl,
                              float* __restrict__ out) {
  const int idx = blockIdx.x * blockDim.x + threadIdx.x;
  if (idx >= 64 * 10) return;
  const int n = idx / 10, o = idx % 10;
  const float* p = pooled + (size_t)n * 128;
  const float* w = ql + (size_t)o * 128;
  float s = 0.f;
#pragma unroll 4
  for (int c = 0; c < 128; ++c) s += p[c] * w[c];
  out[idx] = s * (1.f / 3136.f) + bl[o];
}

// ---------------------------------------------------------------- launch
extern "C" void kernel_launch(void* const* d_in, const int* in_sizes, int n_in,
                              void* d_out, int out_size, void* d_ws,
                              size_t ws_size, hipStream_t stream) {
  const float* x  = (const float*)d_in[0];
  const float* w1 = (const float*)d_in[1];
  const float* g1 = (const float*)d_in[2];
  const float* b1 = (const float*)d_in[3];
  const float* m1 = (const float*)d_in[4];
  const float* v1 = (const float*)d_in[5];
  const float* w2 = (const float*)d_in[6];
  const float* g2 = (const float*)d_in[7];
  const float* b2 = (const float*)d_in[8];
  const float* m2 = (const float*)d_in[9];
  const float* v2 = (const float*)d_in[10];
  const float* w3 = (const float*)d_in[11];
  const float* g3 = (const float*)d_in[12];
  const float* b3 = (const float*)d_in[13];
  const float* m3 = (const float*)d_in[14];
  const float* v3 = (const float*)d_in[15];
  const float* wl = (const float*)d_in[16];
  const float* bl = (const float*)d_in[17];
  float* out = (float*)d_out;

  // ---- workspace layout ----
  float* Wf = (float*)d_ws;
  float* red = Wf;                // 16
  float* pooled = red + 16;       // 8192 (zeroed with red in one memset)
  float* q1t = pooled + 8192;     // 864
  float* ql = q1t + 864;          // 1280
  float* s1 = ql + 1280;  float* bb1 = s1 + 32;
  float* s2 = bb1 + 32;   float* bb2 = s2 + 64;
  float* s3 = bb2 + 64;   float* bb3 = s3 + 128;
  unsigned short* Us = (unsigned short*)(bb3 + 128);
  unsigned short* w2t = Us;                 // 18432
  unsigned short* w3t = w2t + 18432;        // 73728
  unsigned short* act1 = w3t + 73728;       // 64*12544*32 = 25690112
  // total ~52 MB < ws_size (act2 eliminated)

  // ---- prep ----
  hipMemsetAsync(red, 0, (16 + 8192) * sizeof(float), stream);
  tern_phase1<<<dim3(288, 4), 256, 0, stream>>>(w1, w2, w3, wl, 864, 18432,
                                                73728, 1280, red);
  tern_phase2<<<dim3(288, 4), 256, 0, stream>>>(w1, w2, w3, wl, 864, 18432,
                                                73728, 1280, red);
  prep_all<<<370, 256, 0, stream>>>(w1, w2, w3, wl, g1, b1, m1, v1, g2, b2,
                                    m2, v2, g3, b3, m3, v3, red, q1t, ql, s1,
                                    bb1, s2, bb2, s3, bb3, w2t, w3t);

  // ---- network ----
  conv1_v2<<<dim3(56, 64), 256, 0, stream>>>(x, q1t, s1, bb1, act1);
  conv23_fused<<<dim3(49, 64), 256, 0, stream>>>(act1, w2t, w3t, s2, bb2, s3,
                                                 bb3, pooled);
  linear_kernel<<<3, 256, 0, stream>>>(pooled, ql, bl, out);
}